// Round 9
// baseline (1295.242 us; speedup 1.0000x reference)
//
#include <hip/hip_runtime.h>

#define N_FEAT 64
#define NBINS 256
#define NB2 263                       // 256 bins + 7 dummy slots; odd stride:
                                      // bank = (lane*7 + idx) % 32, gcd(7,32)=1
#define HIST_FLOATS (N_FEAT * NBINS)  // 16384 per histogram type
#define NBLOCKS 256                   // 1 block per CU (LDS-capped)
#define BLOCK_T 128                   // 2 waves: wave0 = grad, wave1 = hess
#define CHUNK 32                      // rows per pipeline stage
#define BATCH 8                       // rows per dedup/RMW window
#define PARTIAL_FLOATS (2 * HIST_FLOATS)   // 32768 per-block flush
#define WS_PARTIAL_BYTES ((size_t)NBLOCKS * PARTIAL_FLOATS * sizeof(float))

// Bins for rows [c, c+32): lane = feature column -> 256B coalesced row loads.
__device__ __forceinline__ void load_bins(const int* __restrict__ Xl,
    int c, int rend, int (&bins)[CHUNK])
{
    if (c + CHUNK <= rend) {
        #pragma unroll
        for (int j = 0; j < CHUNK; ++j)
            bins[j] = Xl[(size_t)(c + j) * N_FEAT];
    } else {
        #pragma unroll
        for (int j = 0; j < CHUNK; ++j) {
            int r = c + j; r = r < rend ? r : rend - 1;  // dup rows get val 0
            bins[j] = Xl[(size_t)r * N_FEAT];
        }
    }
}

// Values for rows [c, c+32): wave-uniform address -> scalar (SGPR) loads.
__device__ __forceinline__ void load_vals(const float* __restrict__ vp,
    int c, int rend, float (&val)[CHUNK])
{
    if (c + CHUNK <= rend) {
        #pragma unroll
        for (int j = 0; j < CHUNK / 4; ++j) {
            const float4 v4 = *reinterpret_cast<const float4*>(vp + c + 4 * j);
            val[4*j+0] = v4.x; val[4*j+1] = v4.y; val[4*j+2] = v4.z; val[4*j+3] = v4.w;
        }
    } else {
        #pragma unroll
        for (int j = 0; j < CHUNK; ++j)
            val[j] = (c + j < rend) ? vp[c + j] : 0.f;
    }
}

// Exclusive-ownership RMW, 8-row dedup window: route each row's value to the
// FIRST row with an equal bin; later dups write their own (already-counted-
// elsewhere) residue to per-lane dummy slots 256..262. All 8 RMW addresses
// are then pairwise distinct -> 8 ds_reads in flight per lgkm wait (halves
// latency exposures vs the round-6/7/8 quad window). Same-wave DS ops are
// in-order, so cross-window RAW on the same bin is safe.
__device__ __forceinline__ void process_chunk(float* __restrict__ hrow,
    const int (&bins)[CHUNK], const float (&val)[CHUNK])
{
    #pragma unroll
    for (int q = 0; q < CHUNK / BATCH; ++q) {
        int   b[BATCH], a[BATCH];
        float s[BATCH];
        #pragma unroll
        for (int j = 0; j < BATCH; ++j) {
            b[j] = bins[q * BATCH + j];
            s[j] = val[q * BATCH + j];
        }
        a[0] = b[0];
        #pragma unroll
        for (int j = 1; j < BATCH; ++j) {
            bool p = true;                      // b[j] unseen so far
            #pragma unroll
            for (int i = 0; i < j; ++i) {
                const bool c = (b[j] == b[i]) && p;   // first match only
                s[i] += c ? s[j] : 0.f;
                p = p && (b[j] != b[i]);
            }
            a[j] = p ? b[j] : (NBINS + j - 1);  // dup -> dummy slot
        }
        float t[BATCH];
        #pragma unroll
        for (int j = 0; j < BATCH; ++j) t[j] = hrow[a[j]];
        #pragma unroll
        for (int j = 0; j < BATCH; ++j) hrow[a[j]] = t[j] + s[j];
    }
}

// Kernel A: atomic-free histogram. Wave 0: lane f owns grad-hist of feature
// f; wave 1: hess-hist. Add-values are wave-uniform (SGPR), X row loads are
// fully coalesced 256B, and the only DS traffic is the irreducible RMW.
__global__ __launch_bounds__(BLOCK_T, 1) void _split_hist_kernel(
    const int* __restrict__ X, const float* __restrict__ grad,
    const float* __restrict__ hess, float* __restrict__ ws, int n, int mode)
{
    __shared__ float hist[2][N_FEAT][NB2];   // 134,656 B
    const int tid  = threadIdx.x;
    const int w    = tid >> 6;               // 0 = grad, 1 = hess
    const int lane = tid & 63;               // feature

    for (int i = tid; i < 2 * N_FEAT * NB2; i += BLOCK_T)
        (&hist[0][0][0])[i] = 0.f;
    __syncthreads();

    const float* vp   = w ? hess : grad;     // wave-uniform select
    const int*   Xl   = X + lane;
    float*       hrow = &hist[w][lane][0];

    const int R    = (((n + NBLOCKS - 1) / NBLOCKS) + CHUNK - 1) / CHUNK * CHUNK;
    const int rbeg = blockIdx.x * R;
    const int rend = min(rbeg + R, n);

    if (rbeg < rend) {
        int   binsA[CHUNK], binsB[CHUNK];
        float valA[CHUNK], valB[CHUNK];
        load_bins(Xl, rbeg, rend, binsA);
        load_vals(vp, rbeg, rend, valA);
        for (int c = rbeg; c < rend; c += 2 * CHUNK) {
            const int c1 = c + CHUNK, c2 = c + 2 * CHUNK;
            if (c1 < rend) {
                load_bins(Xl, c1, rend, binsB);
                load_vals(vp, c1, rend, valB);
            }
            process_chunk(hrow, binsA, valA);
            if (c1 < rend) {
                if (c2 < rend) {
                    load_bins(Xl, c2, rend, binsA);
                    load_vals(vp, c2, rend, valA);
                }
                process_chunk(hrow, binsB, valB);
            }
        }
    }
    __syncthreads();

    // Flush (pad-stripped). mode=1: per-block partials ws[block][type][feat][bin];
    // mode=0: f32 global atomics into ws[type][feat][bin] (ws pre-zeroed).
    if (mode) {
        float* dst = ws + (size_t)blockIdx.x * PARTIAL_FLOATS;
        for (int i = tid; i < PARTIAL_FLOATS; i += BLOCK_T) {
            const int ty  = i >> 14;
            const int fe  = (i >> 8) & 63;
            const int bin = i & 255;
            dst[i] = hist[ty][fe][bin];
        }
    } else {
        for (int i = tid; i < PARTIAL_FLOATS; i += BLOCK_T) {
            const int ty  = i >> 14;
            const int fe  = (i >> 8) & 63;
            const int bin = i & 255;
            unsafeAtomicAdd(&ws[i], hist[ty][fe][bin]);
        }
    }
}

// Kernel B: reduce partials (mode=1, 8x unrolled with 4 accumulators for
// MLP) + inclusive scan over 256 bins for each of 128 rows.
__global__ __launch_bounds__(NBINS) void _split_scan_kernel(
    const float* __restrict__ ws, float* __restrict__ out, int mode)
{
    __shared__ float s[NBINS];
    const int row = blockIdx.x;
    const int t   = threadIdx.x;

    float acc = 0.f;
    if (mode) {
        const size_t slot = (size_t)row * NBINS + t;
        float a0 = 0.f, a1 = 0.f, a2 = 0.f, a3 = 0.f;
        #pragma unroll 8
        for (int p = 0; p < NBLOCKS; p += 4) {
            a0 += ws[(size_t)(p + 0) * PARTIAL_FLOATS + slot];
            a1 += ws[(size_t)(p + 1) * PARTIAL_FLOATS + slot];
            a2 += ws[(size_t)(p + 2) * PARTIAL_FLOATS + slot];
            a3 += ws[(size_t)(p + 3) * PARTIAL_FLOATS + slot];
        }
        acc = (a0 + a1) + (a2 + a3);
    } else {
        acc = ws[row * NBINS + t];
    }
    s[t] = acc;
    __syncthreads();

    #pragma unroll
    for (int off = 1; off < NBINS; off <<= 1) {
        float x = (t >= off) ? s[t - off] : 0.f;
        __syncthreads();
        s[t] += x;
        __syncthreads();
    }
    out[row * NBINS + t] = s[t];
}

extern "C" void kernel_launch(void* const* d_in, const int* in_sizes, int n_in,
                              void* d_out, int out_size, void* d_ws, size_t ws_size,
                              hipStream_t stream) {
    const int*   X    = (const int*)d_in[0];
    const float* grad = (const float*)d_in[1];
    const float* hess = (const float*)d_in[2];
    float*       out  = (float*)d_out;
    float*       ws   = (float*)d_ws;
    const int n = in_sizes[1];   // N_SAMPLES

    const int mode = (ws_size >= WS_PARTIAL_BYTES) ? 1 : 0;
    if (!mode)
        hipMemsetAsync(d_ws, 0, 2 * HIST_FLOATS * sizeof(float), stream);

    hipLaunchKernelGGL(_split_hist_kernel, dim3(NBLOCKS), dim3(BLOCK_T), 0, stream,
                       X, grad, hess, ws, n, mode);
    hipLaunchKernelGGL(_split_scan_kernel, dim3(2 * N_FEAT), dim3(NBINS), 0, stream,
                       ws, out, mode);
}

// Round 11
// 1095.586 us; speedup vs baseline: 1.1822x; 1.1822x over previous
//
#include <hip/hip_runtime.h>

#define N_FEAT 64
#define NBINS 256
#define NB2 264                       // 256 bins + dummies: A-quad 256..258, B-quad 260..263
#define HIST_FLOATS (N_FEAT * NBINS)  // 16384 per histogram type
#define NBLOCKS 256                   // 1 block per CU (LDS-capped)
#define BLOCK_T 128                   // 2 waves: wave0 = grad, wave1 = hess
#define CHUNK 32                      // rows per pipeline stage
#define PARTIAL_FLOATS (2 * HIST_FLOATS)   // 32768 per-block flush
#define WS_PARTIAL_BYTES ((size_t)NBLOCKS * PARTIAL_FLOATS * sizeof(float))

// Bins for rows [c, c+32): lane = feature column -> 256B coalesced row loads.
__device__ __forceinline__ void load_bins(const int* __restrict__ Xl,
    int c, int rend, int (&bins)[CHUNK])
{
    if (c + CHUNK <= rend) {
        #pragma unroll
        for (int j = 0; j < CHUNK; ++j)
            bins[j] = Xl[(size_t)(c + j) * N_FEAT];
    } else {
        #pragma unroll
        for (int j = 0; j < CHUNK; ++j) {
            int r = c + j; r = r < rend ? r : rend - 1;  // dup rows get val 0
            bins[j] = Xl[(size_t)r * N_FEAT];
        }
    }
}

// Values for rows [c, c+32): wave-uniform address -> scalar (SGPR) loads.
__device__ __forceinline__ void load_vals(const float* __restrict__ vp,
    int c, int rend, float (&val)[CHUNK])
{
    if (c + CHUNK <= rend) {
        #pragma unroll
        for (int j = 0; j < CHUNK / 4; ++j) {
            const float4 v4 = *reinterpret_cast<const float4*>(vp + c + 4 * j);
            val[4*j+0] = v4.x; val[4*j+1] = v4.y; val[4*j+2] = v4.z; val[4*j+3] = v4.w;
        }
    } else {
        #pragma unroll
        for (int j = 0; j < CHUNK; ++j)
            val[j] = (c + j < rend) ? vp[c + j] : 0.f;
    }
}

// Exclusive-ownership RMW, 8 rows per lgkm wait via two independent quad
// dedups + a shallow cross-absorb (A's post-dedup addrs are pairwise
// distinct, so each surviving B addr matches at most ONE A slot -> 16
// independent cndmask-adds, no serial prefix chains; round-9's serial-`p`
// nested-loop dedup was a 100+cyc dependent chain and regressed).
__device__ __forceinline__ void process_chunk(float* __restrict__ hrow,
    const int (&bins)[CHUNK], const float (&val)[CHUNK])
{
    #pragma unroll
    for (int w = 0; w < CHUNK / 8; ++w) {
        const int   bA0 = bins[8*w+0], bA1 = bins[8*w+1], bA2 = bins[8*w+2], bA3 = bins[8*w+3];
        const int   bB0 = bins[8*w+4], bB1 = bins[8*w+5], bB2 = bins[8*w+6], bB3 = bins[8*w+7];
        const float vA0 = val[8*w+0], vA1 = val[8*w+1], vA2 = val[8*w+2], vA3 = val[8*w+3];
        const float vB0 = val[8*w+4], vB1 = val[8*w+5], vB2 = val[8*w+6], vB3 = val[8*w+7];

        // quad dedup A (first-match routing; proven r6-r8 logic)
        const bool a10 = bA1 == bA0;
        const bool a20 = bA2 == bA0, a21 = bA2 == bA1;
        const bool a30 = bA3 == bA0, a31 = bA3 == bA1, a32 = bA3 == bA2;
        float sA0 = vA0 + (a10 ? vA1 : 0.f) + (a20 ? vA2 : 0.f) + (a30 ? vA3 : 0.f);
        float sA1 = vA1 + ((!a20 && a21) ? vA2 : 0.f) + ((!a30 && a31) ? vA3 : 0.f);
        float sA2 = vA2 + ((!a30 && !a31 && a32) ? vA3 : 0.f);
        float sA3 = vA3;
        const int aA0 = bA0;
        const int aA1 = a10                 ? NBINS + 0 : bA1;
        const int aA2 = (a20 || a21)        ? NBINS + 1 : bA2;
        const int aA3 = (a30 || a31 || a32) ? NBINS + 2 : bA3;

        // quad dedup B (independent of A -> issues in parallel)
        const bool c10 = bB1 == bB0;
        const bool c20 = bB2 == bB0, c21 = bB2 == bB1;
        const bool c30 = bB3 == bB0, c31 = bB3 == bB1, c32 = bB3 == bB2;
        float sB0 = vB0 + (c10 ? vB1 : 0.f) + (c20 ? vB2 : 0.f) + (c30 ? vB3 : 0.f);
        float sB1 = vB1 + ((!c20 && c21) ? vB2 : 0.f) + ((!c30 && c31) ? vB3 : 0.f);
        float sB2 = vB2 + ((!c30 && !c31 && c32) ? vB3 : 0.f);
        float sB3 = vB3;
        int aB0 = bB0;
        int aB1 = c10                 ? NBINS + 5 : bB1;
        int aB2 = (c20 || c21)        ? NBINS + 6 : bB2;
        int aB3 = (c30 || c31 || c32) ? NBINS + 7 : bB3;

        // cross-absorb B into A (dummies >=256 never match; <=1 match per j)
        {
            const bool m0 = aB0 == aA0, m1 = aB0 == aA1, m2 = aB0 == aA2, m3 = aB0 == aA3;
            sA0 += m0 ? sB0 : 0.f; sA1 += m1 ? sB0 : 0.f;
            sA2 += m2 ? sB0 : 0.f; sA3 += m3 ? sB0 : 0.f;
            aB0 = (m0 || m1 || m2 || m3) ? NBINS + 4 : aB0;
        }
        {
            const bool m0 = aB1 == aA0, m1 = aB1 == aA1, m2 = aB1 == aA2, m3 = aB1 == aA3;
            sA0 += m0 ? sB1 : 0.f; sA1 += m1 ? sB1 : 0.f;
            sA2 += m2 ? sB1 : 0.f; sA3 += m3 ? sB1 : 0.f;
            aB1 = (m0 || m1 || m2 || m3) ? NBINS + 5 : aB1;
        }
        {
            const bool m0 = aB2 == aA0, m1 = aB2 == aA1, m2 = aB2 == aA2, m3 = aB2 == aA3;
            sA0 += m0 ? sB2 : 0.f; sA1 += m1 ? sB2 : 0.f;
            sA2 += m2 ? sB2 : 0.f; sA3 += m3 ? sB2 : 0.f;
            aB2 = (m0 || m1 || m2 || m3) ? NBINS + 6 : aB2;
        }
        {
            const bool m0 = aB3 == aA0, m1 = aB3 == aA1, m2 = aB3 == aA2, m3 = aB3 == aA3;
            sA0 += m0 ? sB3 : 0.f; sA1 += m1 ? sB3 : 0.f;
            sA2 += m2 ? sB3 : 0.f; sA3 += m3 ? sB3 : 0.f;
            aB3 = (m0 || m1 || m2 || m3) ? NBINS + 7 : aB3;
        }

        // 8 reads -> one wait -> 8 adds -> 8 writes (all addrs distinct)
        const float t0 = hrow[aA0], t1 = hrow[aA1], t2 = hrow[aA2], t3 = hrow[aA3];
        const float t4 = hrow[aB0], t5 = hrow[aB1], t6 = hrow[aB2], t7 = hrow[aB3];
        hrow[aA0] = t0 + sA0; hrow[aA1] = t1 + sA1;
        hrow[aA2] = t2 + sA2; hrow[aA3] = t3 + sA3;
        hrow[aB0] = t4 + sB0; hrow[aB1] = t5 + sB1;
        hrow[aB2] = t6 + sB2; hrow[aB3] = t7 + sB3;
    }
}

// Kernel A: atomic-free histogram. Wave 0: lane f owns grad-hist of feature
// f; wave 1: hess-hist. Add-values are wave-uniform (SGPR), X row loads are
// fully coalesced 256B, and the only DS traffic is the irreducible RMW.
__global__ __launch_bounds__(BLOCK_T, 1) void _split_hist_kernel(
    const int* __restrict__ X, const float* __restrict__ grad,
    const float* __restrict__ hess, float* __restrict__ ws, int n, int mode)
{
    __shared__ float hist[2][N_FEAT][NB2];   // 135,168 B
    const int tid  = threadIdx.x;
    const int w    = tid >> 6;               // 0 = grad, 1 = hess
    const int lane = tid & 63;               // feature

    for (int i = tid; i < 2 * N_FEAT * NB2; i += BLOCK_T)
        (&hist[0][0][0])[i] = 0.f;
    __syncthreads();

    const float* vp   = w ? hess : grad;     // wave-uniform select
    const int*   Xl   = X + lane;
    float*       hrow = &hist[w][lane][0];

    const int R    = (((n + NBLOCKS - 1) / NBLOCKS) + CHUNK - 1) / CHUNK * CHUNK;
    const int rbeg = blockIdx.x * R;
    const int rend = min(rbeg + R, n);

    if (rbeg < rend) {
        int   binsA[CHUNK], binsB[CHUNK];
        float valA[CHUNK], valB[CHUNK];
        load_bins(Xl, rbeg, rend, binsA);
        load_vals(vp, rbeg, rend, valA);
        for (int c = rbeg; c < rend; c += 2 * CHUNK) {
            const int c1 = c + CHUNK, c2 = c + 2 * CHUNK;
            if (c1 < rend) {
                load_bins(Xl, c1, rend, binsB);
                load_vals(vp, c1, rend, valB);
            }
            process_chunk(hrow, binsA, valA);
            if (c1 < rend) {
                if (c2 < rend) {
                    load_bins(Xl, c2, rend, binsA);
                    load_vals(vp, c2, rend, valA);
                }
                process_chunk(hrow, binsB, valB);
            }
        }
    }
    __syncthreads();

    // Flush (pad-stripped). mode=1: per-block partials ws[block][type][feat][bin];
    // mode=0: f32 global atomics into ws[type][feat][bin] (ws pre-zeroed).
    if (mode) {
        float* dst = ws + (size_t)blockIdx.x * PARTIAL_FLOATS;
        for (int i = tid; i < PARTIAL_FLOATS; i += BLOCK_T) {
            const int ty  = i >> 14;
            const int fe  = (i >> 8) & 63;
            const int bin = i & 255;
            dst[i] = hist[ty][fe][bin];
        }
    } else {
        for (int i = tid; i < PARTIAL_FLOATS; i += BLOCK_T) {
            const int ty  = i >> 14;
            const int fe  = (i >> 8) & 63;
            const int bin = i & 255;
            unsafeAtomicAdd(&ws[i], hist[ty][fe][bin]);
        }
    }
}

// Kernel B: reduce partials (mode=1, 8x unrolled with 4 accumulators for
// MLP) + inclusive scan over 256 bins for each of 128 rows.
__global__ __launch_bounds__(NBINS) void _split_scan_kernel(
    const float* __restrict__ ws, float* __restrict__ out, int mode)
{
    __shared__ float s[NBINS];
    const int row = blockIdx.x;
    const int t   = threadIdx.x;

    float acc = 0.f;
    if (mode) {
        const size_t slot = (size_t)row * NBINS + t;
        float a0 = 0.f, a1 = 0.f, a2 = 0.f, a3 = 0.f;
        #pragma unroll 8
        for (int p = 0; p < NBLOCKS; p += 4) {
            a0 += ws[(size_t)(p + 0) * PARTIAL_FLOATS + slot];
            a1 += ws[(size_t)(p + 1) * PARTIAL_FLOATS + slot];
            a2 += ws[(size_t)(p + 2) * PARTIAL_FLOATS + slot];
            a3 += ws[(size_t)(p + 3) * PARTIAL_FLOATS + slot];
        }
        acc = (a0 + a1) + (a2 + a3);
    } else {
        acc = ws[row * NBINS + t];
    }
    s[t] = acc;
    __syncthreads();

    #pragma unroll
    for (int off = 1; off < NBINS; off <<= 1) {
        float x = (t >= off) ? s[t - off] : 0.f;
        __syncthreads();
        s[t] += x;
        __syncthreads();
    }
    out[row * NBINS + t] = s[t];
}

extern "C" void kernel_launch(void* const* d_in, const int* in_sizes, int n_in,
                              void* d_out, int out_size, void* d_ws, size_t ws_size,
                              hipStream_t stream) {
    const int*   X    = (const int*)d_in[0];
    const float* grad = (const float*)d_in[1];
    const float* hess = (const float*)d_in[2];
    float*       out  = (float*)d_out;
    float*       ws   = (float*)d_ws;
    const int n = in_sizes[1];   // N_SAMPLES

    const int mode = (ws_size >= WS_PARTIAL_BYTES) ? 1 : 0;
    if (!mode)
        hipMemsetAsync(d_ws, 0, 2 * HIST_FLOATS * sizeof(float), stream);

    hipLaunchKernelGGL(_split_hist_kernel, dim3(NBLOCKS), dim3(BLOCK_T), 0, stream,
                       X, grad, hess, ws, n, mode);
    hipLaunchKernelGGL(_split_scan_kernel, dim3(2 * N_FEAT), dim3(NBINS), 0, stream,
                       ws, out, mode);
}

// Round 12
// 1020.713 us; speedup vs baseline: 1.2690x; 1.0734x over previous
//
#include <hip/hip_runtime.h>

#define N_FEAT 64
#define NBINS 256
#define LB 128                        // local bins per half-region
#define REGION 133                    // 128 bins + 4 quad dummies + pad; odd -> banks spread
#define HIST_FLOATS (N_FEAT * NBINS)  // 16384 per histogram type
#define NBLOCKS 256                   // 1 block per CU (LDS-capped)
#define BLOCK_T 256                   // 4 waves: (type, bin-half) = (w>>1, w&1)
#define CHUNK 32                      // rows per pipeline stage
#define NREGION (2 * N_FEAT * 2)      // 256 owner regions (type x feat x half)
#define PARTIAL_FLOATS (2 * HIST_FLOATS)   // 32768 per-block flush
#define WS_PARTIAL_BYTES ((size_t)NBLOCKS * PARTIAL_FLOATS * sizeof(float))

// Bins for rows [c, c+32): lane = feature column -> 256B coalesced row loads.
__device__ __forceinline__ void load_bins(const int* __restrict__ Xl,
    int c, int rend, int (&bins)[CHUNK])
{
    if (c + CHUNK <= rend) {
        #pragma unroll
        for (int j = 0; j < CHUNK; ++j)
            bins[j] = Xl[(size_t)(c + j) * N_FEAT];
    } else {
        #pragma unroll
        for (int j = 0; j < CHUNK; ++j) {
            int r = c + j; r = r < rend ? r : rend - 1;  // dup rows get val 0
            bins[j] = Xl[(size_t)r * N_FEAT];
        }
    }
}

// Values for rows [c, c+32): wave-uniform address -> scalar (SGPR) loads.
__device__ __forceinline__ void load_vals(const float* __restrict__ vp,
    int c, int rend, float (&val)[CHUNK])
{
    if (c + CHUNK <= rend) {
        #pragma unroll
        for (int j = 0; j < CHUNK / 4; ++j) {
            const float4 v4 = *reinterpret_cast<const float4*>(vp + c + 4 * j);
            val[4*j+0] = v4.x; val[4*j+1] = v4.y; val[4*j+2] = v4.z; val[4*j+3] = v4.w;
        }
    } else {
        #pragma unroll
        for (int j = 0; j < CHUNK; ++j)
            val[j] = (c + j < rend) ? vp[c + j] : 0.f;
    }
}

// Round-8 quad-dedup RMW (proven optimum window) + bin-half ownership:
// entries whose bin lies in the other half, or which are dups, route to
// per-quad dummy slots LB..LB+3 (never flushed). Real addrs are pairwise
// distinct (dedup + same-half => distinct bin&127), so 4 reads share one
// lgkm wait. The owning lane in the partner wave performs the same merge
// and writes the true bin -- each (type,feat,bin) lands exactly once.
__device__ __forceinline__ void process_chunk(float* __restrict__ hrow,
    int halfbit, const int (&bins)[CHUNK], const float (&val)[CHUNK])
{
    #pragma unroll
    for (int q = 0; q < CHUNK / 4; ++q) {
        const int   b0 = bins[4*q+0], b1 = bins[4*q+1], b2 = bins[4*q+2], b3 = bins[4*q+3];
        const float v0 = val[4*q+0], v1 = val[4*q+1], v2 = val[4*q+2], v3 = val[4*q+3];
        const bool e10 = b1 == b0;
        const bool e20 = b2 == b0, e21 = b2 == b1;
        const bool e30 = b3 == b0, e31 = b3 == b1, e32 = b3 == b2;
        const float s0 = v0 + (e10 ? v1 : 0.f) + (e20 ? v2 : 0.f) + (e30 ? v3 : 0.f);
        const float s1 = v1 + ((!e20 && e21) ? v2 : 0.f) + ((!e30 && e31) ? v3 : 0.f);
        const float s2 = v2 + ((!e30 && !e31 && e32) ? v3 : 0.f);
        const float s3 = v3;
        const bool r0 = (b0 & LB) == halfbit;
        const bool r1 = ((b1 & LB) == halfbit) && !e10;
        const bool r2 = ((b2 & LB) == halfbit) && !(e20 || e21);
        const bool r3 = ((b3 & LB) == halfbit) && !(e30 || e31 || e32);
        const int a0 = r0 ? (b0 & (LB - 1)) : (LB + 0);
        const int a1 = r1 ? (b1 & (LB - 1)) : (LB + 1);
        const int a2 = r2 ? (b2 & (LB - 1)) : (LB + 2);
        const int a3 = r3 ? (b3 & (LB - 1)) : (LB + 3);
        const float t0 = hrow[a0], t1 = hrow[a1], t2 = hrow[a2], t3 = hrow[a3];
        hrow[a0] = t0 + s0;
        hrow[a1] = t1 + s1;
        hrow[a2] = t2 + s2;
        hrow[a3] = t3 + s3;
    }
}

// Kernel A: atomic-free histogram, 4 waves (one per SIMD). Wave w: lane f
// owns (type=w>>1, feature=f, bin-half=w&1) -- 256 exclusive regions. X row
// loads fully coalesced 256B (waves share lines via L1); add-values are
// wave-uniform SGPR floats; the only DS traffic is the RMW stream.
__global__ __launch_bounds__(BLOCK_T, 1) void _split_hist_kernel(
    const int* __restrict__ X, const float* __restrict__ grad,
    const float* __restrict__ hess, float* __restrict__ ws, int n, int mode)
{
    __shared__ float hist[NREGION * REGION];   // 136,192 B
    const int tid  = threadIdx.x;
    const int w    = tid >> 6;
    const int type = w >> 1;                   // 0 = grad, 1 = hess
    const int half = w & 1;                    // bin half
    const int lane = tid & 63;                 // feature

    for (int i = tid; i < NREGION * REGION; i += BLOCK_T)
        hist[i] = 0.f;
    __syncthreads();

    const float* vp      = type ? hess : grad;           // wave-uniform
    const int*   Xl      = X + lane;
    float*       hrow    = &hist[(((type * N_FEAT + lane) << 1) + half) * REGION];
    const int    halfbit = half << 7;

    const int R    = (((n + NBLOCKS - 1) / NBLOCKS) + CHUNK - 1) / CHUNK * CHUNK;
    const int rbeg = blockIdx.x * R;
    const int rend = min(rbeg + R, n);

    if (rbeg < rend) {
        int   binsA[CHUNK], binsB[CHUNK];
        float valA[CHUNK], valB[CHUNK];
        load_bins(Xl, rbeg, rend, binsA);
        load_vals(vp, rbeg, rend, valA);
        for (int c = rbeg; c < rend; c += 2 * CHUNK) {
            const int c1 = c + CHUNK, c2 = c + 2 * CHUNK;
            if (c1 < rend) {
                load_bins(Xl, c1, rend, binsB);
                load_vals(vp, c1, rend, valB);
            }
            process_chunk(hrow, halfbit, binsA, valA);
            if (c1 < rend) {
                if (c2 < rend) {
                    load_bins(Xl, c2, rend, binsA);
                    load_vals(vp, c2, rend, valA);
                }
                process_chunk(hrow, halfbit, binsB, valB);
            }
        }
    }
    __syncthreads();

    // Flush real bins only. mode=1: per-block partials ws[block][ty][fe][bin];
    // mode=0: f32 global atomics into ws[ty][fe][bin] (ws pre-zeroed).
    if (mode) {
        float* dst = ws + (size_t)blockIdx.x * PARTIAL_FLOATS;
        for (int i = tid; i < PARTIAL_FLOATS; i += BLOCK_T) {
            const int ty  = i >> 14;
            const int fe  = (i >> 8) & 63;
            const int bin = i & 255;
            const int reg = ((ty * N_FEAT + fe) << 1) + (bin >> 7);
            dst[i] = hist[reg * REGION + (bin & (LB - 1))];
        }
    } else {
        for (int i = tid; i < PARTIAL_FLOATS; i += BLOCK_T) {
            const int ty  = i >> 14;
            const int fe  = (i >> 8) & 63;
            const int bin = i & 255;
            const int reg = ((ty * N_FEAT + fe) << 1) + (bin >> 7);
            unsafeAtomicAdd(&ws[i], hist[reg * REGION + (bin & (LB - 1))]);
        }
    }
}

// Kernel B: reduce partials (mode=1, 8x unrolled with 4 accumulators for
// MLP) + inclusive scan over 256 bins for each of 128 rows.
__global__ __launch_bounds__(NBINS) void _split_scan_kernel(
    const float* __restrict__ ws, float* __restrict__ out, int mode)
{
    __shared__ float s[NBINS];
    const int row = blockIdx.x;
    const int t   = threadIdx.x;

    float acc = 0.f;
    if (mode) {
        const size_t slot = (size_t)row * NBINS + t;
        float a0 = 0.f, a1 = 0.f, a2 = 0.f, a3 = 0.f;
        #pragma unroll 8
        for (int p = 0; p < NBLOCKS; p += 4) {
            a0 += ws[(size_t)(p + 0) * PARTIAL_FLOATS + slot];
            a1 += ws[(size_t)(p + 1) * PARTIAL_FLOATS + slot];
            a2 += ws[(size_t)(p + 2) * PARTIAL_FLOATS + slot];
            a3 += ws[(size_t)(p + 3) * PARTIAL_FLOATS + slot];
        }
        acc = (a0 + a1) + (a2 + a3);
    } else {
        acc = ws[row * NBINS + t];
    }
    s[t] = acc;
    __syncthreads();

    #pragma unroll
    for (int off = 1; off < NBINS; off <<= 1) {
        float x = (t >= off) ? s[t - off] : 0.f;
        __syncthreads();
        s[t] += x;
        __syncthreads();
    }
    out[row * NBINS + t] = s[t];
}

extern "C" void kernel_launch(void* const* d_in, const int* in_sizes, int n_in,
                              void* d_out, int out_size, void* d_ws, size_t ws_size,
                              hipStream_t stream) {
    const int*   X    = (const int*)d_in[0];
    const float* grad = (const float*)d_in[1];
    const float* hess = (const float*)d_in[2];
    float*       out  = (float*)d_out;
    float*       ws   = (float*)d_ws;
    const int n = in_sizes[1];   // N_SAMPLES

    const int mode = (ws_size >= WS_PARTIAL_BYTES) ? 1 : 0;
    if (!mode)
        hipMemsetAsync(d_ws, 0, 2 * HIST_FLOATS * sizeof(float), stream);

    hipLaunchKernelGGL(_split_hist_kernel, dim3(NBLOCKS), dim3(BLOCK_T), 0, stream,
                       X, grad, hess, ws, n, mode);
    hipLaunchKernelGGL(_split_scan_kernel, dim3(2 * N_FEAT), dim3(NBINS), 0, stream,
                       ws, out, mode);
}